// Round 5
// baseline (740.806 us; speedup 1.0000x reference)
//
#include <hip/hip_runtime.h>

#define HDIM 2048
#define NHEAD 16
#define DHEAD 128
#define BATCH 4
#define SEQ 2048
#define AUD 512

typedef unsigned short u16;
typedef unsigned int u32;
typedef __bf16 bf16_t;
typedef bf16_t bf16x8 __attribute__((ext_vector_type(8)));
typedef short short8 __attribute__((ext_vector_type(8)));
typedef float f32x4 __attribute__((ext_vector_type(4)));

typedef const __attribute__((address_space(1))) u32 gas_u32;
typedef __attribute__((address_space(3))) u32 las_u32;

__device__ __forceinline__ float b2f(u16 h) {
  union { u32 u; float f; } v; v.u = ((u32)h) << 16; return v.f;
}
__device__ __forceinline__ u16 f2b(float f) {
  union { float f; u32 u; } v; v.f = f;
  u32 r = (v.u + 0x7FFFu + ((v.u >> 16) & 1u)) >> 16;  // RNE
  return (u16)r;
}

// ------- f32 -> bf16 convert, both inputs in one launch (8 els/thread) -------
__global__ __launch_bounds__(256) void cvt2_k(const float* __restrict__ s0,
                                              u16* __restrict__ d0, int n0,
                                              const float* __restrict__ s1,
                                              u16* __restrict__ d1, int n1) {
  int i = blockIdx.x * 256 + threadIdx.x;
  const float* src; u16* dst; int j;
  if (i < n0) { src = s0; dst = d0; j = i; }
  else { j = i - n0; if (j >= n1) return; src = s1; dst = d1; }
  const float4* s4 = (const float4*)src;
  float4 a = s4[2 * j], b = s4[2 * j + 1];
  short8 o;
  o[0] = (short)f2b(a.x); o[1] = (short)f2b(a.y);
  o[2] = (short)f2b(a.z); o[3] = (short)f2b(a.w);
  o[4] = (short)f2b(b.x); o[5] = (short)f2b(b.y);
  o[6] = (short)f2b(b.z); o[7] = (short)f2b(b.w);
  *(short8*)(dst + (size_t)j * 8) = o;
}

// ---- all-4 weight transpose + convert in one launch: z selects the weight ----
__global__ __launch_bounds__(256) void transpose4_k(
    const float* __restrict__ Wq, const float* __restrict__ Wk,
    const float* __restrict__ Wv, const float* __restrict__ Wo,
    u16* __restrict__ dst4) {
  const float* src = (blockIdx.z == 0) ? Wq
                   : (blockIdx.z == 1) ? Wk
                   : (blockIdx.z == 2) ? Wv : Wo;
  u16* dst = dst4 + (size_t)blockIdx.z * HDIM * HDIM;
  __shared__ float tile[32][33];
  int tx = threadIdx.x, ty = threadIdx.y;  // 32 x 8
  int x = blockIdx.x * 32 + tx;
  int y0 = blockIdx.y * 32;
#pragma unroll
  for (int j = 0; j < 32; j += 8)
    tile[ty + j][tx] = src[(size_t)(y0 + ty + j) * HDIM + x];
  __syncthreads();
  int x2 = y0 + tx;
  int y2 = blockIdx.x * 32;
#pragma unroll
  for (int j = 0; j < 32; j += 8)
    dst[(size_t)(y2 + ty + j) * HDIM + x2] = f2b(tile[tx][ty + j]);
}

// ------------- m97-structure tiled GEMM (128x128, BK=32) -------------
// Kept for the small K/V projections (M=2048 -> 256 blocks keeps all CUs busy).
// cmode: 0 = bf16 C row-major; 1 = Vt scatter (bf16); 2 = f32 C row-major.
__global__ __launch_bounds__(256) void gemm_bt(
    const u16* __restrict__ A, int lda,
    const u16* __restrict__ Bt, int ldb,
    void* __restrict__ Cv, int ldc,
    const float* __restrict__ bias, float alpha, int M, int N, int K, int cmode) {
  __shared__ u16 As[128 * 32];  // [row][k], rows of 64B
  __shared__ u16 Bs[128 * 32];

  int lane = threadIdx.x & 63;
  int wave = threadIdx.x >> 6;
  // T1: XCD-aware bijective tile swizzle (grid count % 8 == 0)
  int gdx = gridDim.x;
  int id = blockIdx.y * gdx + blockIdx.x;
  int cpx = (gdx * gridDim.y) >> 3;
  int sid = (id & 7) * cpx + (id >> 3);
  int m0 = (sid / gdx) * 128;
  int n0 = (sid % gdx) * 128;
  int wm = (wave & 1) * 64;
  int wn = (wave >> 1) * 64;
  int row16 = lane & 15;
  int quad = lane >> 4;

  int sr = (lane >> 2);
  int sc = (lane & 3) * 8;

  f32x4 acc[4][4];
#pragma unroll
  for (int i = 0; i < 4; i++)
#pragma unroll
    for (int j = 0; j < 4; j++) acc[i][j] = (f32x4){0.f, 0.f, 0.f, 0.f};

  for (int k0 = 0; k0 < K; k0 += 32) {
#pragma unroll
    for (int t = 0; t < 2; t++) {
      int chunk = wave * 2 + t;
      int r = chunk * 16 + sr;
      const u16* ga = A + (size_t)(m0 + r) * lda + k0 + sc;
      const u16* gb = Bt + (size_t)(n0 + r) * ldb + k0 + sc;
      __builtin_amdgcn_global_load_lds((gas_u32*)ga, (las_u32*)(As + chunk * 512), 16, 0, 0);
      __builtin_amdgcn_global_load_lds((gas_u32*)gb, (las_u32*)(Bs + chunk * 512), 16, 0, 0);
    }
    __syncthreads();

    short8 af[4], bf[4];
#pragma unroll
    for (int mt = 0; mt < 4; mt++)
      af[mt] = *(const short8*)(As + (wm + mt * 16 + row16) * 32 + quad * 8);
#pragma unroll
    for (int nt = 0; nt < 4; nt++)
      bf[nt] = *(const short8*)(Bs + (wn + nt * 16 + row16) * 32 + quad * 8);
#pragma unroll
    for (int mt = 0; mt < 4; mt++)
#pragma unroll
      for (int nt = 0; nt < 4; nt++)
        acc[mt][nt] = __builtin_amdgcn_mfma_f32_16x16x32_bf16(
            __builtin_bit_cast(bf16x8, af[mt]), __builtin_bit_cast(bf16x8, bf[nt]),
            acc[mt][nt], 0, 0, 0);
    __syncthreads();
  }

#pragma unroll
  for (int nt = 0; nt < 4; nt++) {
    int nn = n0 + wn + nt * 16 + row16;
    float bv = bias ? bias[nn] : 0.f;
#pragma unroll
    for (int mt = 0; mt < 4; mt++) {
#pragma unroll
      for (int r = 0; r < 4; r++) {
        int mm = m0 + wm + mt * 16 + quad * 4 + r;
        float val = (acc[mt][nt][r] + bv) * alpha;
        if (cmode == 2) {
          ((float*)Cv)[(size_t)mm * ldc + nn] = val;
        } else if (cmode == 1) {
          int bb = mm >> 9, aa = mm & 511;
          int hh = nn >> 7, dd = nn & 127;
          ((u16*)Cv)[((size_t)((bb * 16 + hh) * 128 + dd)) * 512 + aa] = f2b(val);
        } else {
          ((u16*)Cv)[(size_t)mm * ldc + nn] = f2b(val);
        }
      }
    }
  }
}

// ---- big-GEMM: 256x256 tile, BK=32, 4-slot ring, 2 phases/K-tile (T2+T3+T4+T5) ----
// 8 waves (2M x 4N), per-wave output 128x64. LDS 128 KiB (4 slots x 16 KiB x {A,B}).
// Ring ledger (lead 3): iter kt stages slot (kt+3)&3 -- A-half in ph0, B-half in ph1;
// vmcnt(8) once per K-tile (in ph1) => slot kt+1 fully landed before iter kt+1 reads.
__global__ __launch_bounds__(512, 2) void gemm_ring8(
    const u16* __restrict__ A, int lda,
    const u16* __restrict__ Bt, int ldb,
    void* __restrict__ Cv, int ldc,
    const float* __restrict__ bias, float alpha, int K, int cmode) {
  __shared__ u16 As[4][256 * 32];  // 64 KiB
  __shared__ u16 Bs[4][256 * 32];  // 64 KiB

  int tid = threadIdx.x;
  int lane = tid & 63, wave = tid >> 6;  // 8 waves: 2M x 4N
  int wr = wave >> 2, wc = wave & 3;
  int row16 = lane & 15, quad = lane >> 4;
  int cofs = (quad * 8) ^ (((row16 >> 1) & 3) << 3);  // read-side swizzle

  // T1: XCD-aware bijective tile swizzle (grid count % 8 == 0)
  int gdx = gridDim.x;  // N tiles
  int id = blockIdx.y * gdx + blockIdx.x;
  int cpx = (gdx * gridDim.y) >> 3;
  int sid = (id & 7) * cpx + (id >> 3);
  int n0 = (sid % gdx) * 256;
  int m0 = (sid / gdx) * 256;

  int r0 = tid >> 2;
  int c0 = ((tid & 3) ^ ((r0 >> 1) & 3)) * 8;

  f32x4 acc[8][4];
#pragma unroll
  for (int i = 0; i < 8; i++)
#pragma unroll
    for (int j = 0; j < 4; j++) acc[i][j] = (f32x4){0.f, 0.f, 0.f, 0.f};

  auto stageA = [&](int slot, int k0) {
#pragma unroll
    for (int l = 0; l < 2; l++) {
      int row = l * 128 + r0;
      __builtin_amdgcn_global_load_lds(
          (gas_u32*)(A + (size_t)(m0 + row) * lda + k0 + c0),
          (las_u32*)(&As[slot][(l * 512 + tid) * 8]), 16, 0, 0);
    }
  };
  auto stageB = [&](int slot, int k0) {
#pragma unroll
    for (int l = 0; l < 2; l++) {
      int row = l * 128 + r0;
      __builtin_amdgcn_global_load_lds(
          (gas_u32*)(Bt + (size_t)(n0 + row) * ldb + k0 + c0),
          (las_u32*)(&Bs[slot][(l * 512 + tid) * 8]), 16, 0, 0);
    }
  };

  int NT = K >> 5;  // K-tiles of 32 (assumes NT >= 3)
  stageA(0, 0);  stageB(0, 0);
  stageA(1, 32); stageB(1, 32);
  stageA(2, 64); stageB(2, 64);
  asm volatile("s_waitcnt vmcnt(8)" ::: "memory");  // slot 0 landed
  __builtin_amdgcn_s_barrier();

  for (int kt = 0; kt < NT; ++kt) {
    int slot = kt & 3;
    int sp = (kt + 3) & 3;
    bool pf = (kt + 3) < NT;
    const u16* as = &As[slot][0];
    const u16* bs = &Bs[slot][0];

    // ---- phase 0: B frags + A frags (mi 0-3), stage A(kt+3), MFMA quadrant ----
    short8 bfr[4], af[4];
#pragma unroll
    for (int ni = 0; ni < 4; ni++)
      bfr[ni] = *(const short8*)(bs + (wc * 64 + ni * 16 + row16) * 32 + cofs);
#pragma unroll
    for (int mi = 0; mi < 4; mi++)
      af[mi] = *(const short8*)(as + (wr * 128 + mi * 16 + row16) * 32 + cofs);
    if (pf) stageA(sp, (kt + 3) << 5);
    __builtin_amdgcn_s_barrier();
    asm volatile("s_waitcnt lgkmcnt(0)" ::: "memory");
    __builtin_amdgcn_s_setprio(1);
#pragma unroll
    for (int mi = 0; mi < 4; mi++)
#pragma unroll
      for (int ni = 0; ni < 4; ni++)
        acc[mi][ni] = __builtin_amdgcn_mfma_f32_16x16x32_bf16(
            __builtin_bit_cast(bf16x8, af[mi]), __builtin_bit_cast(bf16x8, bfr[ni]),
            acc[mi][ni], 0, 0, 0);
    __builtin_amdgcn_s_setprio(0);
    __builtin_amdgcn_s_barrier();

    // ---- phase 1: A frags (mi 4-7), stage B(kt+3), vmcnt ledger, MFMA ----
    short8 ag[4];
#pragma unroll
    for (int mi = 0; mi < 4; mi++)
      ag[mi] = *(const short8*)(as + (wr * 128 + (mi + 4) * 16 + row16) * 32 + cofs);
    if (pf) stageB(sp, (kt + 3) << 5);
    {
      int nf = NT - 2 - kt;  // remaining staged slots newer than kt+1
      if (nf >= 2)      asm volatile("s_waitcnt vmcnt(8)" ::: "memory");
      else if (nf == 1) asm volatile("s_waitcnt vmcnt(4)" ::: "memory");
      else              asm volatile("s_waitcnt vmcnt(0)" ::: "memory");
    }
    __builtin_amdgcn_s_barrier();
    asm volatile("s_waitcnt lgkmcnt(0)" ::: "memory");
    __builtin_amdgcn_s_setprio(1);
#pragma unroll
    for (int mi = 0; mi < 4; mi++)
#pragma unroll
      for (int ni = 0; ni < 4; ni++)
        acc[mi + 4][ni] = __builtin_amdgcn_mfma_f32_16x16x32_bf16(
            __builtin_bit_cast(bf16x8, ag[mi]), __builtin_bit_cast(bf16x8, bfr[ni]),
            acc[mi + 4][ni], 0, 0, 0);
    __builtin_amdgcn_s_setprio(0);
    __builtin_amdgcn_s_barrier();
  }

#pragma unroll
  for (int ni = 0; ni < 4; ni++) {
    int nn = n0 + wc * 64 + ni * 16 + row16;
    float bv = bias ? bias[nn] : 0.f;
#pragma unroll
    for (int mi = 0; mi < 8; mi++) {
#pragma unroll
      for (int r = 0; r < 4; r++) {
        int mm = m0 + wr * 128 + mi * 16 + quad * 4 + r;
        float val = (acc[mi][ni][r] + bv) * alpha;
        if (cmode == 2) ((float*)Cv)[(size_t)mm * ldc + nn] = val;
        else            ((u16*)Cv)[(size_t)mm * ldc + nn] = f2b(val);
      }
    }
  }
}

// ------------- fused flash attention (8-wave, reg-prefetch pipeline) -------------
// grid (16, 64) remapped XCD-chunked; 512 thr = 8 waves, each owns 16 q-rows.
// Round-4 theory: round-3 counters (Mfma 12%, VALU 25%, HBM 13%, Occ 11%) =
// latency-bound at 2 waves/SIMD. 8 waves/block @ <=128 VGPR -> 2 blocks/CU ->
// 4 waves/SIMD (2x TLP). XCD-chunked swizzle: each XCD serves 8 (b,h) pairs
// (K/V 2 MB, L2-resident) -> prefetch returns at L2 latency, FETCH drops.
// Pipeline (round 3, kept): KP is K then P; reg-prefetch of tile kt+1 issued
// after P-write, flies during PV, ds_written after post-PV barrier. LDS
// XOR-swizzle col^((row&7)<<3) everywhere. No setprio (m190 lockstep null).
__global__ __launch_bounds__(512, 4) void flash_k(
    const u16* __restrict__ Q, const u16* __restrict__ K,
    const u16* __restrict__ Vt, const float* __restrict__ mask,
    u16* __restrict__ Ctx) {
  __shared__ u16 KP[128 * 128];  // K-tile [key][dh], then P-tile [q][key]
  __shared__ u16 Vs[128 * 128];  // V-tile [dh][key]

  // XCD-chunked swizzle: 1024 blocks = 8 XCDs x 128; XCD k -> bh in [k*8,k*8+8)
  int id = blockIdx.y * gridDim.x + blockIdx.x;
  int sid = (id & 7) * 128 + (id >> 3);
  int qt = sid & 15, bh = sid >> 4;
  int b = bh >> 4, h = bh & 15;
  int q0 = qt * 128;

  int lane = threadIdx.x & 63, wave = threadIdx.x >> 6;  // 8 waves
  int row16 = lane & 15, quad = lane >> 4;
  int wq = wave * 16;  // wave's 16 q-rows
  int swr = (row16 & 7) << 3;  // read-side swizzle

  const u16* qbase = Q + ((size_t)(b * SEQ + q0)) * HDIM + h * DHEAD;
  const u16* kbase = K + ((size_t)b * AUD) * HDIM + h * DHEAD;
  const u16* vbase = Vt + ((size_t)(b * NHEAD + h)) * DHEAD * AUD;
  const float* mp = mask + b * AUD;

  // Q fragments: 1 m-tile x 4 k-steps
  short8 qf[4];
#pragma unroll
  for (int ks = 0; ks < 4; ks++)
    qf[ks] = *(const short8*)(qbase + (size_t)(wq + row16) * HDIM + ks * 32 + quad * 8);

  f32x4 oacc[8];
  float lacc[4];
#pragma unroll
  for (int nt = 0; nt < 8; nt++) oacc[nt] = (f32x4){0.f, 0.f, 0.f, 0.f};
#pragma unroll
  for (int r = 0; r < 4; r++) lacc[r] = 0.f;

  int sl = (lane >> 4);        // staging: row within 4-row chunk
  int scol = (lane & 15) * 8;  // dh/key offset (16B chunk)

  // ---- prologue: stage tile 0 via global_load_lds (source pre-swizzled) ----
#pragma unroll
  for (int t = 0; t < 4; t++) {
    int c = wave * 4 + t;
    int r = c * 4 + sl;
    int csw = scol ^ ((r & 7) << 3);
    __builtin_amdgcn_global_load_lds(
        (gas_u32*)(kbase + (size_t)r * HDIM + csw),
        (las_u32*)(KP + c * 512), 16, 0, 0);
    __builtin_amdgcn_global_load_lds(
        (gas_u32*)(vbase + (size_t)r * AUD + csw),
        (las_u32*)(Vs + c * 512), 16, 0, 0);
  }
  __syncthreads();

  for (int kt = 0; kt < 4; kt++) {
    // ---- S = Q @ K^T : wave's 16q x 128key ----
    f32x4 sacc[8];
#pragma unroll
    for (int nt = 0; nt < 8; nt++) sacc[nt] = (f32x4){0.f, 0.f, 0.f, 0.f};
#pragma unroll
    for (int ks = 0; ks < 4; ks++) {
      short8 bf[8];
      int cofs = (ks * 32 + quad * 8) ^ swr;
#pragma unroll
      for (int nt = 0; nt < 8; nt++)
        bf[nt] = *(const short8*)(KP + (nt * 16 + row16) * 128 + cofs);
#pragma unroll
      for (int nt = 0; nt < 8; nt++)
        sacc[nt] = __builtin_amdgcn_mfma_f32_16x16x32_bf16(
            __builtin_bit_cast(bf16x8, qf[ks]), __builtin_bit_cast(bf16x8, bf[nt]),
            sacc[nt], 0, 0, 0);
    }

    // ---- e = exp(s + mask*-1e4); accumulate l ----
#pragma unroll
    for (int nt = 0; nt < 8; nt++) {
      float mval = mp[kt * 128 + nt * 16 + row16] * (-10000.0f);
#pragma unroll
      for (int r = 0; r < 4; r++) {
        float e = __expf(sacc[nt][r] + mval);
        sacc[nt][r] = e;
        lacc[r] += e;
      }
    }

    // B1: all waves done reading KP-as-K.
    asm volatile("s_waitcnt lgkmcnt(0)" ::: "memory");
    __builtin_amdgcn_s_barrier();

    // ---- write P (bf16) into KP as [q][key], swizzled by q-row ----
#pragma unroll
    for (int nt = 0; nt < 8; nt++)
#pragma unroll
      for (int r = 0; r < 4; r++) {
        int prow = wq + quad * 4 + r;
        KP[prow * 128 + ((nt * 16 + row16) ^ ((prow & 7) << 3))] = f2b(sacc[nt][r]);
      }

    // ---- issue reg-prefetch of tile kt+1 (flies during PV) ----
    short8 kreg[4], vreg[4];
    if (kt < 3) {
#pragma unroll
      for (int t = 0; t < 4; t++) {
        int r = wq + t * 4 + sl;
        kreg[t] = *(const short8*)(kbase + (size_t)((kt + 1) * 128 + r) * HDIM + scol);
        vreg[t] = *(const short8*)(vbase + (size_t)r * AUD + (kt + 1) * 128 + scol);
      }
    }

    // ---- O += P @ V (P rows are wave-private: no barrier after P-write) ----
#pragma unroll
    for (int ks = 0; ks < 4; ks++) {
      short8 af, bf[8];
      int cofs = (ks * 32 + quad * 8) ^ swr;
      af = *(const short8*)(KP + (wq + row16) * 128 + cofs);
#pragma unroll
      for (int nt = 0; nt < 8; nt++)
        bf[nt] = *(const short8*)(Vs + (nt * 16 + row16) * 128 + cofs);
#pragma unroll
      for (int nt = 0; nt < 8; nt++)
        oacc[nt] = __builtin_amdgcn_mfma_f32_16x16x32_bf16(
            __builtin_bit_cast(bf16x8, af), __builtin_bit_cast(bf16x8, bf[nt]),
            oacc[nt], 0, 0, 0);
    }

    // B3: everyone done reading KP(P)/Vs; prefetch loads still in flight.
    asm volatile("s_waitcnt lgkmcnt(0)" ::: "memory");
    __builtin_amdgcn_s_barrier();

    // ---- stage tile kt+1 from registers (swizzled ds_write_b128) ----
    if (kt < 3) {
      asm volatile("s_waitcnt vmcnt(0)" ::: "memory");
#pragma unroll
      for (int t = 0; t < 4; t++) {
        int r = wq + t * 4 + sl;
        int cs = scol ^ ((r & 7) << 3);
        *(short8*)(KP + r * 128 + cs) = kreg[t];
        *(short8*)(Vs + r * 128 + cs) = vreg[t];
      }
    }
    // B4: staged data visible to all before next iteration's reads.
    asm volatile("s_waitcnt lgkmcnt(0)" ::: "memory");
    __builtin_amdgcn_s_barrier();
  }

  // reduce l over the 16 lanes of each quad (keys dimension)
#pragma unroll
  for (int r = 0; r < 4; r++) {
    float s = lacc[r];
    for (int off = 1; off < 16; off <<= 1) s += __shfl_xor(s, off, 64);
    lacc[r] = 1.0f / s;
  }

  // write ctx: C/D layout col=dh (lane&15), row=q (quad*4+r)
  u16* cb = Ctx + ((size_t)(b * SEQ + q0 + wq)) * HDIM + h * DHEAD;
#pragma unroll
  for (int nt = 0; nt < 8; nt++)
#pragma unroll
    for (int r = 0; r < 4; r++)
      cb[(size_t)(quad * 4 + r) * HDIM + nt * 16 + row16] =
          f2b(oacc[nt][r] * lacc[r]);
}

// ---- residual + LayerNorm (f32 in/out): out = LN(O + hs)*gamma + beta, in place ----
__global__ __launch_bounds__(256) void ln_k(const float* O,
                                            const float* __restrict__ hs,
                                            const float* __restrict__ gamma,
                                            const float* __restrict__ beta,
                                            float* out) {
  size_t rowoff = (size_t)blockIdx.x * HDIM;
  float x[8], sum = 0.f, sq = 0.f;
#pragma unroll
  for (int i = 0; i < 8; i++) {
    int idx = threadIdx.x + 256 * i;
    float v = O[rowoff + idx] + hs[rowoff + idx];
    x[i] = v;
    sum += v;
    sq += v * v;
  }
  for (int off = 32; off; off >>= 1) {
    sum += __shfl_xor(sum, off, 64);
    sq += __shfl_xor(sq, off, 64);
  }
  __shared__ float red[8];
  int wave = threadIdx.x >> 6, lane = threadIdx.x & 63;
  if (lane == 0) { red[wave] = sum; red[4 + wave] = sq; }
  __syncthreads();
  sum = red[0] + red[1] + red[2] + red[3];
  sq = red[4] + red[5] + red[6] + red[7];
  float mu = sum * (1.0f / HDIM);
  float var = sq * (1.0f / HDIM) - mu * mu;
  float inv = rsqrtf(var + 1e-5f);
#pragma unroll
  for (int i = 0; i < 8; i++) {
    int idx = threadIdx.x + 256 * i;
    out[rowoff + idx] = (x[i] - mu) * inv * gamma[idx] + beta[idx];
  }
}

extern "C" void kernel_launch(void* const* d_in, const int* in_sizes, int n_in,
                              void* d_out, int out_size, void* d_ws, size_t ws_size,
                              hipStream_t stream) {
  (void)in_sizes; (void)n_in; (void)out_size; (void)ws_size;
  const float* hs   = (const float*)d_in[0];
  const float* at   = (const float*)d_in[1];
  const float* mask = (const float*)d_in[2];
  const float* Wq = (const float*)d_in[3];  const float* bq = (const float*)d_in[4];
  const float* Wk = (const float*)d_in[5];  const float* bk = (const float*)d_in[6];
  const float* Wv = (const float*)d_in[7];  const float* bv = (const float*)d_in[8];
  const float* Wo = (const float*)d_in[9];  const float* bo = (const float*)d_in[10];
  const float* gamma = (const float*)d_in[11];
  const float* beta  = (const float*)d_in[12];
  float* out = (float*)d_out;
  u16* ws = (u16*)d_ws;

  // workspace (bf16 elements). Total 79,691,776 els = 159.4 MB (ws has 256 MB).
  u16* hsb = ws;               // 16,777,216  bf16(hidden_states)
  u16* atb = ws + 16777216;    //  4,194,304  bf16(audio_tokens)
  u16* wT4 = ws + 20971520;    // 16,777,216  4x transposed bf16 weights
  u16* Q   = ws + 37748736;    // 16,777,216  (8192 x 2048, pre-scaled)
  u16* Kb  = ws + 54525952;    //  4,194,304  (2048 x 2048)
  u16* Vt  = ws + 58720256;    //  4,194,304  [b,h,d,a]
  u16* Ctx = ws + 62914560;    // 16,777,216  (8192 x 2048)
  u16* wTq = wT4;
  u16* wTk = wT4 + 4194304;
  u16* wTv = wT4 + 8388608;
  u16* wTo = wT4 + 12582912;
  // O (pre-LN, f32) lives in d_out; ln_k is same-thread in-place: safe.

  // both input converts in one launch
  cvt2_k<<<10240, 256, 0, stream>>>(hs, hsb, 2097152, at, atb, 524288);
  // all 4 weight transposes in one launch
  transpose4_k<<<dim3(64, 64, 4), dim3(32, 8), 0, stream>>>(Wq, Wk, Wv, Wo, wT4);

  const float qscale = 0.08838834764831845f;  // 1/sqrt(128)

  // Q = (hs @ Wq + bq) * qscale : M=8192 N=2048 K=2048 (256x256 tiles -> 8x32)
  gemm_ring8<<<dim3(8, 32), 512, 0, stream>>>(hsb, HDIM, wTq, HDIM, Q, HDIM,
                                              bq, qscale, 2048, 0);
  // K = at @ Wk + bk : M=2048 (128x128 tiles -> 16x16)
  gemm_bt<<<dim3(16, 16), 256, 0, stream>>>(atb, HDIM, wTk, HDIM, Kb, HDIM,
                                            bk, 1.0f, 2048, 2048, 2048, 0);
  // V = at @ Wv + bv, written transposed per head into Vt
  gemm_bt<<<dim3(16, 16), 256, 0, stream>>>(atb, HDIM, wTv, HDIM, Vt, HDIM,
                                            bv, 1.0f, 2048, 2048, 2048, 1);

  // fused attention: Ctx = softmax(Q K^T + mask) V
  flash_k<<<dim3(SEQ / 128, BATCH * NHEAD), 512, 0, stream>>>(Q, Kb, Vt, mask, Ctx);

  // O = Ctx @ Wo + bo : M=8192, f32 into d_out (cmode=2)
  gemm_ring8<<<dim3(8, 32), 512, 0, stream>>>(Ctx, HDIM, wTo, HDIM, out, HDIM,
                                              bo, 1.0f, 2048, 2);
  // out = LayerNorm(O + hs) * gamma + beta  (f32, in place over d_out)
  ln_k<<<8192, 256, 0, stream>>>(out, hs, gamma, beta, out);
}

// Round 7
// 565.871 us; speedup vs baseline: 1.3091x; 1.3091x over previous
//
#include <hip/hip_runtime.h>

#define HDIM 2048
#define NHEAD 16
#define DHEAD 128
#define BATCH 4
#define SEQ 2048
#define AUD 512

typedef unsigned short u16;
typedef unsigned int u32;
typedef __bf16 bf16_t;
typedef bf16_t bf16x8 __attribute__((ext_vector_type(8)));
typedef short short8 __attribute__((ext_vector_type(8)));
typedef float f32x4 __attribute__((ext_vector_type(4)));

typedef const __attribute__((address_space(1))) u32 gas_u32;
typedef __attribute__((address_space(3))) u32 las_u32;

__device__ __forceinline__ float b2f(u16 h) {
  union { u32 u; float f; } v; v.u = ((u32)h) << 16; return v.f;
}
__device__ __forceinline__ u16 f2b(float f) {
  union { float f; u32 u; } v; v.f = f;
  u32 r = (v.u + 0x7FFFu + ((v.u >> 16) & 1u)) >> 16;  // RNE
  return (u16)r;
}

// ------- f32 -> bf16 convert, both inputs in one launch (8 els/thread) -------
__global__ __launch_bounds__(256) void cvt2_k(const float* __restrict__ s0,
                                              u16* __restrict__ d0, int n0,
                                              const float* __restrict__ s1,
                                              u16* __restrict__ d1, int n1) {
  int i = blockIdx.x * 256 + threadIdx.x;
  const float* src; u16* dst; int j;
  if (i < n0) { src = s0; dst = d0; j = i; }
  else { j = i - n0; if (j >= n1) return; src = s1; dst = d1; }
  const float4* s4 = (const float4*)src;
  float4 a = s4[2 * j], b = s4[2 * j + 1];
  short8 o;
  o[0] = (short)f2b(a.x); o[1] = (short)f2b(a.y);
  o[2] = (short)f2b(a.z); o[3] = (short)f2b(a.w);
  o[4] = (short)f2b(b.x); o[5] = (short)f2b(b.y);
  o[6] = (short)f2b(b.z); o[7] = (short)f2b(b.w);
  *(short8*)(dst + (size_t)j * 8) = o;
}

// ---- all-4 weight transpose + convert in one launch: z selects the weight ----
__global__ __launch_bounds__(256) void transpose4_k(
    const float* __restrict__ Wq, const float* __restrict__ Wk,
    const float* __restrict__ Wv, const float* __restrict__ Wo,
    u16* __restrict__ dst4) {
  const float* src = (blockIdx.z == 0) ? Wq
                   : (blockIdx.z == 1) ? Wk
                   : (blockIdx.z == 2) ? Wv : Wo;
  u16* dst = dst4 + (size_t)blockIdx.z * HDIM * HDIM;
  __shared__ float tile[32][33];
  int tx = threadIdx.x, ty = threadIdx.y;  // 32 x 8
  int x = blockIdx.x * 32 + tx;
  int y0 = blockIdx.y * 32;
#pragma unroll
  for (int j = 0; j < 32; j += 8)
    tile[ty + j][tx] = src[(size_t)(y0 + ty + j) * HDIM + x];
  __syncthreads();
  int x2 = y0 + tx;
  int y2 = blockIdx.x * 32;
#pragma unroll
  for (int j = 0; j < 32; j += 8)
    dst[(size_t)(y2 + ty + j) * HDIM + x2] = f2b(tile[tx][ty + j]);
}

// ------------- m97-structure tiled GEMM (128x128, BK=32) -------------
// Kept for the small K/V projections (M=2048 -> 256 blocks keeps all CUs busy).
// cmode: 0 = bf16 C row-major; 1 = Vt scatter (bf16); 2 = f32 C row-major.
__global__ __launch_bounds__(256) void gemm_bt(
    const u16* __restrict__ A, int lda,
    const u16* __restrict__ Bt, int ldb,
    void* __restrict__ Cv, int ldc,
    const float* __restrict__ bias, float alpha, int M, int N, int K, int cmode) {
  __shared__ u16 As[128 * 32];  // [row][k], rows of 64B
  __shared__ u16 Bs[128 * 32];

  int lane = threadIdx.x & 63;
  int wave = threadIdx.x >> 6;
  // T1: XCD-aware bijective tile swizzle (grid count % 8 == 0)
  int gdx = gridDim.x;
  int id = blockIdx.y * gdx + blockIdx.x;
  int cpx = (gdx * gridDim.y) >> 3;
  int sid = (id & 7) * cpx + (id >> 3);
  int m0 = (sid / gdx) * 128;
  int n0 = (sid % gdx) * 128;
  int wm = (wave & 1) * 64;
  int wn = (wave >> 1) * 64;
  int row16 = lane & 15;
  int quad = lane >> 4;

  int sr = (lane >> 2);
  int sc = (lane & 3) * 8;

  f32x4 acc[4][4];
#pragma unroll
  for (int i = 0; i < 4; i++)
#pragma unroll
    for (int j = 0; j < 4; j++) acc[i][j] = (f32x4){0.f, 0.f, 0.f, 0.f};

  for (int k0 = 0; k0 < K; k0 += 32) {
#pragma unroll
    for (int t = 0; t < 2; t++) {
      int chunk = wave * 2 + t;
      int r = chunk * 16 + sr;
      const u16* ga = A + (size_t)(m0 + r) * lda + k0 + sc;
      const u16* gb = Bt + (size_t)(n0 + r) * ldb + k0 + sc;
      __builtin_amdgcn_global_load_lds((gas_u32*)ga, (las_u32*)(As + chunk * 512), 16, 0, 0);
      __builtin_amdgcn_global_load_lds((gas_u32*)gb, (las_u32*)(Bs + chunk * 512), 16, 0, 0);
    }
    __syncthreads();

    short8 af[4], bf[4];
#pragma unroll
    for (int mt = 0; mt < 4; mt++)
      af[mt] = *(const short8*)(As + (wm + mt * 16 + row16) * 32 + quad * 8);
#pragma unroll
    for (int nt = 0; nt < 4; nt++)
      bf[nt] = *(const short8*)(Bs + (wn + nt * 16 + row16) * 32 + quad * 8);
#pragma unroll
    for (int mt = 0; mt < 4; mt++)
#pragma unroll
      for (int nt = 0; nt < 4; nt++)
        acc[mt][nt] = __builtin_amdgcn_mfma_f32_16x16x32_bf16(
            __builtin_bit_cast(bf16x8, af[mt]), __builtin_bit_cast(bf16x8, bf[nt]),
            acc[mt][nt], 0, 0, 0);
    __syncthreads();
  }

#pragma unroll
  for (int nt = 0; nt < 4; nt++) {
    int nn = n0 + wn + nt * 16 + row16;
    float bv = bias ? bias[nn] : 0.f;
#pragma unroll
    for (int mt = 0; mt < 4; mt++) {
#pragma unroll
      for (int r = 0; r < 4; r++) {
        int mm = m0 + wm + mt * 16 + quad * 4 + r;
        float val = (acc[mt][nt][r] + bv) * alpha;
        if (cmode == 2) {
          ((float*)Cv)[(size_t)mm * ldc + nn] = val;
        } else if (cmode == 1) {
          int bb = mm >> 9, aa = mm & 511;
          int hh = nn >> 7, dd = nn & 127;
          ((u16*)Cv)[((size_t)((bb * 16 + hh) * 128 + dd)) * 512 + aa] = f2b(val);
        } else {
          ((u16*)Cv)[(size_t)mm * ldc + nn] = f2b(val);
        }
      }
    }
  }
}

// ---- big-GEMM: 256x256 tile, BK=32, 4-slot ring, 2 phases/K-tile (T2+T3+T4+T5) ----
// 8 waves (2M x 4N), per-wave output 128x64. LDS 128 KiB (4 slots x 16 KiB x {A,B}).
// Ring ledger (lead 3): iter kt stages slot (kt+3)&3 -- A-half in ph0, B-half in ph1;
// vmcnt(8) once per K-tile (in ph1) => slot kt+1 fully landed before iter kt+1 reads.
__global__ __launch_bounds__(512, 2) void gemm_ring8(
    const u16* __restrict__ A, int lda,
    const u16* __restrict__ Bt, int ldb,
    void* __restrict__ Cv, int ldc,
    const float* __restrict__ bias, float alpha, int K, int cmode) {
  __shared__ u16 As[4][256 * 32];  // 64 KiB
  __shared__ u16 Bs[4][256 * 32];  // 64 KiB

  int tid = threadIdx.x;
  int lane = tid & 63, wave = tid >> 6;  // 8 waves: 2M x 4N
  int wr = wave >> 2, wc = wave & 3;
  int row16 = lane & 15, quad = lane >> 4;
  int cofs = (quad * 8) ^ (((row16 >> 1) & 3) << 3);  // read-side swizzle

  // T1: XCD-aware bijective tile swizzle (grid count % 8 == 0)
  int gdx = gridDim.x;  // N tiles
  int id = blockIdx.y * gdx + blockIdx.x;
  int cpx = (gdx * gridDim.y) >> 3;
  int sid = (id & 7) * cpx + (id >> 3);
  int n0 = (sid % gdx) * 256;
  int m0 = (sid / gdx) * 256;

  int r0 = tid >> 2;
  int c0 = ((tid & 3) ^ ((r0 >> 1) & 3)) * 8;

  f32x4 acc[8][4];
#pragma unroll
  for (int i = 0; i < 8; i++)
#pragma unroll
    for (int j = 0; j < 4; j++) acc[i][j] = (f32x4){0.f, 0.f, 0.f, 0.f};

  auto stageA = [&](int slot, int k0) {
#pragma unroll
    for (int l = 0; l < 2; l++) {
      int row = l * 128 + r0;
      __builtin_amdgcn_global_load_lds(
          (gas_u32*)(A + (size_t)(m0 + row) * lda + k0 + c0),
          (las_u32*)(&As[slot][(l * 512 + tid) * 8]), 16, 0, 0);
    }
  };
  auto stageB = [&](int slot, int k0) {
#pragma unroll
    for (int l = 0; l < 2; l++) {
      int row = l * 128 + r0;
      __builtin_amdgcn_global_load_lds(
          (gas_u32*)(Bt + (size_t)(n0 + row) * ldb + k0 + c0),
          (las_u32*)(&Bs[slot][(l * 512 + tid) * 8]), 16, 0, 0);
    }
  };

  int NT = K >> 5;  // K-tiles of 32 (assumes NT >= 3)
  stageA(0, 0);  stageB(0, 0);
  stageA(1, 32); stageB(1, 32);
  stageA(2, 64); stageB(2, 64);
  asm volatile("s_waitcnt vmcnt(8)" ::: "memory");  // slot 0 landed
  __builtin_amdgcn_s_barrier();

  for (int kt = 0; kt < NT; ++kt) {
    int slot = kt & 3;
    int sp = (kt + 3) & 3;
    bool pf = (kt + 3) < NT;
    const u16* as = &As[slot][0];
    const u16* bs = &Bs[slot][0];

    // ---- phase 0: B frags + A frags (mi 0-3), stage A(kt+3), MFMA quadrant ----
    short8 bfr[4], af[4];
#pragma unroll
    for (int ni = 0; ni < 4; ni++)
      bfr[ni] = *(const short8*)(bs + (wc * 64 + ni * 16 + row16) * 32 + cofs);
#pragma unroll
    for (int mi = 0; mi < 4; mi++)
      af[mi] = *(const short8*)(as + (wr * 128 + mi * 16 + row16) * 32 + cofs);
    if (pf) stageA(sp, (kt + 3) << 5);
    __builtin_amdgcn_s_barrier();
    asm volatile("s_waitcnt lgkmcnt(0)" ::: "memory");
    __builtin_amdgcn_s_setprio(1);
#pragma unroll
    for (int mi = 0; mi < 4; mi++)
#pragma unroll
      for (int ni = 0; ni < 4; ni++)
        acc[mi][ni] = __builtin_amdgcn_mfma_f32_16x16x32_bf16(
            __builtin_bit_cast(bf16x8, af[mi]), __builtin_bit_cast(bf16x8, bfr[ni]),
            acc[mi][ni], 0, 0, 0);
    __builtin_amdgcn_s_setprio(0);
    __builtin_amdgcn_s_barrier();

    // ---- phase 1: A frags (mi 4-7), stage B(kt+3), vmcnt ledger, MFMA ----
    short8 ag[4];
#pragma unroll
    for (int mi = 0; mi < 4; mi++)
      ag[mi] = *(const short8*)(as + (wr * 128 + (mi + 4) * 16 + row16) * 32 + cofs);
    if (pf) stageB(sp, (kt + 3) << 5);
    {
      int nf = NT - 2 - kt;  // remaining staged slots newer than kt+1
      if (nf >= 2)      asm volatile("s_waitcnt vmcnt(8)" ::: "memory");
      else if (nf == 1) asm volatile("s_waitcnt vmcnt(4)" ::: "memory");
      else              asm volatile("s_waitcnt vmcnt(0)" ::: "memory");
    }
    __builtin_amdgcn_s_barrier();
    asm volatile("s_waitcnt lgkmcnt(0)" ::: "memory");
    __builtin_amdgcn_s_setprio(1);
#pragma unroll
    for (int mi = 0; mi < 4; mi++)
#pragma unroll
      for (int ni = 0; ni < 4; ni++)
        acc[mi + 4][ni] = __builtin_amdgcn_mfma_f32_16x16x32_bf16(
            __builtin_bit_cast(bf16x8, ag[mi]), __builtin_bit_cast(bf16x8, bfr[ni]),
            acc[mi + 4][ni], 0, 0, 0);
    __builtin_amdgcn_s_setprio(0);
    __builtin_amdgcn_s_barrier();
  }

#pragma unroll
  for (int ni = 0; ni < 4; ni++) {
    int nn = n0 + wc * 64 + ni * 16 + row16;
    float bv = bias ? bias[nn] : 0.f;
#pragma unroll
    for (int mi = 0; mi < 8; mi++) {
#pragma unroll
      for (int r = 0; r < 4; r++) {
        int mm = m0 + wr * 128 + mi * 16 + quad * 4 + r;
        float val = (acc[mi][ni][r] + bv) * alpha;
        if (cmode == 2) ((float*)Cv)[(size_t)mm * ldc + nn] = val;
        else            ((u16*)Cv)[(size_t)mm * ldc + nn] = f2b(val);
      }
    }
  }
}

// ---------------- fused flash attention (round-2 config + XCD swizzle) ----------------
// Round-6 NOTE: byte-identical resubmit of round 5 (bench aborted in pytest with
// infra-anomalous timings; all flash components previously passed in rounds 2-4:
// body==round2, barrier-removal==rounds3/4, swizzle==GEMMs rounds 2-4; all
// global/LDS indices re-audited in-bounds). If it aborts again, next round
// bisects by re-adding the P->PV barrier.
// 256 thr = 4 waves, each owns 32 q-rows. Per-tile global_load_lds staging.
// LDS XOR-swizzle col^((row&7)<<3) on KP/Vs. No setprio (m190).
// P-write -> PV barrier removed (wave-private P rows).
// XCD-chunked block swizzle: XCD k serves bh in [k*8, k*8+8) -> K/V (2 MB) stay
// L2-resident across that XCD's 16 q-tile blocks.
__global__ __launch_bounds__(256) void flash_k(
    const u16* __restrict__ Q, const u16* __restrict__ K,
    const u16* __restrict__ Vt, const float* __restrict__ mask,
    u16* __restrict__ Ctx) {
  __shared__ u16 KP[128 * 128];  // K-tile [key][dh], then P-tile [q][key]
  __shared__ u16 Vs[128 * 128];  // V-tile [dh][key]

  // XCD-chunked swizzle: 1024 blocks = 8 XCDs x 128; XCD k -> bh in [k*8,k*8+8)
  int id = blockIdx.y * gridDim.x + blockIdx.x;
  int sid = (id & 7) * 128 + (id >> 3);
  int qt = sid & 15, bh = sid >> 4;
  int b = bh >> 4, h = bh & 15;
  int q0 = qt * 128;

  int lane = threadIdx.x & 63, wave = threadIdx.x >> 6;
  int row16 = lane & 15, quad = lane >> 4;
  int wq = wave * 32;  // wave's 32 q-rows
  int swr = (row16 & 7) << 3;  // read-side swizzle

  const u16* qbase = Q + ((size_t)(b * SEQ + q0)) * HDIM + h * DHEAD;
  const u16* kbase = K + ((size_t)b * AUD) * HDIM + h * DHEAD;
  const u16* vbase = Vt + ((size_t)(b * NHEAD + h)) * DHEAD * AUD;
  const float* mp = mask + b * AUD;

  short8 qf[2][4];
#pragma unroll
  for (int mt = 0; mt < 2; mt++)
#pragma unroll
    for (int ks = 0; ks < 4; ks++)
      qf[mt][ks] = *(const short8*)(qbase + (size_t)(wq + mt * 16 + row16) * HDIM +
                                    ks * 32 + quad * 8);

  f32x4 oacc[2][8];
  float lacc[2][4];
#pragma unroll
  for (int mt = 0; mt < 2; mt++) {
#pragma unroll
    for (int nt = 0; nt < 8; nt++) oacc[mt][nt] = (f32x4){0.f, 0.f, 0.f, 0.f};
#pragma unroll
    for (int r = 0; r < 4; r++) lacc[mt][r] = 0.f;
  }

  int sl = (lane >> 4);
  int scol = (lane & 15) * 8;

  for (int kt = 0; kt < 4; kt++) {
#pragma unroll
    for (int t = 0; t < 8; t++) {
      int c = wave * 8 + t;
      int r = c * 4 + sl;
      int csw = scol ^ ((r & 7) << 3);
      __builtin_amdgcn_global_load_lds(
          (gas_u32*)(kbase + (size_t)(kt * 128 + r) * HDIM + csw),
          (las_u32*)(KP + c * 512), 16, 0, 0);
      __builtin_amdgcn_global_load_lds(
          (gas_u32*)(vbase + (size_t)r * AUD + kt * 128 + csw),
          (las_u32*)(Vs + c * 512), 16, 0, 0);
    }
    __syncthreads();

    f32x4 sacc[2][8];
#pragma unroll
    for (int mt = 0; mt < 2; mt++)
#pragma unroll
      for (int nt = 0; nt < 8; nt++) sacc[mt][nt] = (f32x4){0.f, 0.f, 0.f, 0.f};
#pragma unroll
    for (int ks = 0; ks < 4; ks++) {
      short8 bf[8];
      int cofs = (ks * 32 + quad * 8) ^ swr;
#pragma unroll
      for (int nt = 0; nt < 8; nt++)
        bf[nt] = *(const short8*)(KP + (nt * 16 + row16) * 128 + cofs);
#pragma unroll
      for (int mt = 0; mt < 2; mt++)
#pragma unroll
        for (int nt = 0; nt < 8; nt++)
          sacc[mt][nt] = __builtin_amdgcn_mfma_f32_16x16x32_bf16(
              __builtin_bit_cast(bf16x8, qf[mt][ks]), __builtin_bit_cast(bf16x8, bf[nt]),
              sacc[mt][nt], 0, 0, 0);
    }

#pragma unroll
    for (int nt = 0; nt < 8; nt++) {
      float mval = mp[kt * 128 + nt * 16 + row16] * (-10000.0f);
#pragma unroll
      for (int mt = 0; mt < 2; mt++)
#pragma unroll
        for (int r = 0; r < 4; r++) {
          float e = __expf(sacc[mt][nt][r] + mval);
          sacc[mt][nt][r] = e;
          lacc[mt][r] += e;
        }
    }
    __syncthreads();  // all waves done reading KP-as-K

    // write P (bf16) into KP as [q][key], swizzled by q-row
#pragma unroll
    for (int mt = 0; mt < 2; mt++)
#pragma unroll
      for (int nt = 0; nt < 8; nt++)
#pragma unroll
        for (int r = 0; r < 4; r++) {
          int prow = wq + mt * 16 + quad * 4 + r;
          KP[prow * 128 + ((nt * 16 + row16) ^ ((prow & 7) << 3))] =
              f2b(sacc[mt][nt][r]);
        }
    // (no barrier: each wave reads back only its own 32 P-rows)

    // O += P @ V
#pragma unroll
    for (int ks = 0; ks < 4; ks++) {
      short8 af[2], bf[8];
      int cofs = (ks * 32 + quad * 8) ^ swr;
#pragma unroll
      for (int mt = 0; mt < 2; mt++)
        af[mt] = *(const short8*)(KP + (wq + mt * 16 + row16) * 128 + cofs);
#pragma unroll
      for (int nt = 0; nt < 8; nt++)
        bf[nt] = *(const short8*)(Vs + (nt * 16 + row16) * 128 + cofs);
#pragma unroll
      for (int mt = 0; mt < 2; mt++)
#pragma unroll
        for (int nt = 0; nt < 8; nt++)
          oacc[mt][nt] = __builtin_amdgcn_mfma_f32_16x16x32_bf16(
              __builtin_bit_cast(bf16x8, af[mt]), __builtin_bit_cast(bf16x8, bf[nt]),
              oacc[mt][nt], 0, 0, 0);
    }
    __syncthreads();  // done reading KP(P)/Vs before next stage
  }

  // reduce l over the 16 lanes of each quad (keys dimension)
#pragma unroll
  for (int mt = 0; mt < 2; mt++)
#pragma unroll
    for (int r = 0; r < 4; r++) {
      float s = lacc[mt][r];
      for (int off = 1; off < 16; off <<= 1) s += __shfl_xor(s, off, 64);
      lacc[mt][r] = 1.0f / s;
    }

  // write ctx: C/D layout col=dh (lane&15), row=q (quad*4+r)
  u16* cb = Ctx + ((size_t)(b * SEQ + q0 + wq)) * HDIM + h * DHEAD;
#pragma unroll
  for (int mt = 0; mt < 2; mt++)
#pragma unroll
    for (int nt = 0; nt < 8; nt++)
#pragma unroll
      for (int r = 0; r < 4; r++)
        cb[(size_t)(mt * 16 + quad * 4 + r) * HDIM + nt * 16 + row16] =
            f2b(oacc[mt][nt][r] * lacc[mt][r]);
}

// ---- residual + LayerNorm (f32 in/out): out = LN(O + hs)*gamma + beta, in place ----
__global__ __launch_bounds__(256) void ln_k(const float* O,
                                            const float* __restrict__ hs,
                                            const float* __restrict__ gamma,
                                            const float* __restrict__ beta,
                                            float* out) {
  size_t rowoff = (size_t)blockIdx.x * HDIM;
  float x[8], sum = 0.f, sq = 0.f;
#pragma unroll
  for (int i = 0; i < 8; i++) {
    int idx = threadIdx.x + 256 * i;
    float v = O[rowoff + idx] + hs[rowoff + idx];
    x[i] = v;
    sum += v;
    sq += v * v;
  }
  for (int off = 32; off; off >>= 1) {
    sum += __shfl_xor(sum, off, 64);
    sq += __shfl_xor(sq, off, 64);
  }
  __shared__ float red[8];
  int wave = threadIdx.x >> 6, lane = threadIdx.x & 63;
  if (lane == 0) { red[wave] = sum; red[4 + wave] = sq; }
  __syncthreads();
  sum = red[0] + red[1] + red[2] + red[3];
  sq = red[4] + red[5] + red[6] + red[7];
  float mu = sum * (1.0f / HDIM);
  float var = sq * (1.0f / HDIM) - mu * mu;
  float inv = rsqrtf(var + 1e-5f);
#pragma unroll
  for (int i = 0; i < 8; i++) {
    int idx = threadIdx.x + 256 * i;
    out[rowoff + idx] = (x[i] - mu) * inv * gamma[idx] + beta[idx];
  }
}

extern "C" void kernel_launch(void* const* d_in, const int* in_sizes, int n_in,
                              void* d_out, int out_size, void* d_ws, size_t ws_size,
                              hipStream_t stream) {
  (void)in_sizes; (void)n_in; (void)out_size; (void)ws_size;
  const float* hs   = (const float*)d_in[0];
  const float* at   = (const float*)d_in[1];
  const float* mask = (const float*)d_in[2];
  const float* Wq = (const float*)d_in[3];  const float* bq = (const float*)d_in[4];
  const float* Wk = (const float*)d_in[5];  const float* bk = (const float*)d_in[6];
  const float* Wv = (const float*)d_in[7];  const float* bv = (const float*)d_in[8];
  const float* Wo = (const float*)d_in[9];  const float* bo = (const float*)d_in[10];
  const float* gamma = (const float*)d_in[11];
  const float* beta  = (const float*)d_in[12];
  float* out = (float*)d_out;
  u16* ws = (u16*)d_ws;

  // workspace (bf16 elements). Total 79,691,776 els = 159.4 MB (ws has 256 MB).
  u16* hsb = ws;               // 16,777,216  bf16(hidden_states)
  u16* atb = ws + 16777216;    //  4,194,304  bf16(audio_tokens)
  u16* wT4 = ws + 20971520;    // 16,777,216  4x transposed bf16 weights
  u16* Q   = ws + 37748736;    // 16,777,216  (8192 x 2048, pre-scaled)
  u16* Kb  = ws + 54525952;    //  4,194,304  (2048 x 2048)
  u16* Vt  = ws + 58720256;    //  4,194,304  [b,h,d,a]
  u16* Ctx = ws + 62914560;    // 16,777,216  (8192 x 2048)
  u16* wTq = wT4;
  u16* wTk = wT4 + 4194304;
  u16* wTv = wT4 + 8388608;
  u16* wTo = wT4 + 12582912;
  // O (pre-LN, f32) lives in d_out; ln_k is same-thread in-place: safe.

  // both input converts in one launch
  cvt2_k<<<10240, 256, 0, stream>>>(hs, hsb, 2097152, at, atb, 524288);
  // all 4 weight transposes in one launch
  transpose4_k<<<dim3(64, 64, 4), dim3(32, 8), 0, stream>>>(Wq, Wk, Wv, Wo, wT4);

  const float qscale = 0.08838834764831845f;  // 1/sqrt(128)

  // Q = (hs @ Wq + bq) * qscale : M=8192 N=2048 K=2048 (256x256 tiles -> 8x32)
  gemm_ring8<<<dim3(8, 32), 512, 0, stream>>>(hsb, HDIM, wTq, HDIM, Q, HDIM,
                                              bq, qscale, 2048, 0);
  // K = at @ Wk + bk : M=2048 (128x128 tiles -> 16x16)
  gemm_bt<<<dim3(16, 16), 256, 0, stream>>>(atb, HDIM, wTk, HDIM, Kb, HDIM,
                                            bk, 1.0f, 2048, 2048, 2048, 0);
  // V = at @ Wv + bv, written transposed per head into Vt
  gemm_bt<<<dim3(16, 16), 256, 0, stream>>>(atb, HDIM, wTv, HDIM, Vt, HDIM,
                                            bv, 1.0f, 2048, 2048, 2048, 1);

  // fused attention: Ctx = softmax(Q K^T + mask) V
  flash_k<<<dim3(SEQ / 128, BATCH * NHEAD), 256, 0, stream>>>(Q, Kb, Vt, mask, Ctx);

  // O = Ctx @ Wo + bo : M=8192, f32 into d_out (cmode=2)
  gemm_ring8<<<dim3(8, 32), 512, 0, stream>>>(Ctx, HDIM, wTo, HDIM, out, HDIM,
                                              bo, 1.0f, 2048, 2);
  // out = LayerNorm(O + hs) * gamma + beta  (f32, in place over d_out)
  ln_k<<<8192, 256, 0, stream>>>(out, hs, gamma, beta, out);
}

// Round 9
// 514.281 us; speedup vs baseline: 1.4405x; 1.1003x over previous
//
#include <hip/hip_runtime.h>

#define HDIM 2048
#define NHEAD 16
#define DHEAD 128
#define BATCH 4
#define SEQ 2048
#define AUD 512

typedef unsigned short u16;
typedef unsigned int u32;
typedef __bf16 bf16_t;
typedef bf16_t bf16x8 __attribute__((ext_vector_type(8)));
typedef short short8 __attribute__((ext_vector_type(8)));
typedef float f32x4 __attribute__((ext_vector_type(4)));

typedef const __attribute__((address_space(1))) u32 gas_u32;
typedef __attribute__((address_space(3))) u32 las_u32;

__device__ __forceinline__ float b2f(u16 h) {
  union { u32 u; float f; } v; v.u = ((u32)h) << 16; return v.f;
}
__device__ __forceinline__ u16 f2b(float f) {
  union { float f; u32 u; } v; v.f = f;
  u32 r = (v.u + 0x7FFFu + ((v.u >> 16) & 1u)) >> 16;  // RNE
  return (u16)r;
}

// ------- f32 -> bf16 convert, both inputs in one launch (8 els/thread) -------
__global__ __launch_bounds__(256) void cvt2_k(const float* __restrict__ s0,
                                              u16* __restrict__ d0, int n0,
                                              const float* __restrict__ s1,
                                              u16* __restrict__ d1, int n1) {
  int i = blockIdx.x * 256 + threadIdx.x;
  const float* src; u16* dst; int j;
  if (i < n0) { src = s0; dst = d0; j = i; }
  else { j = i - n0; if (j >= n1) return; src = s1; dst = d1; }
  const float4* s4 = (const float4*)src;
  float4 a = s4[2 * j], b = s4[2 * j + 1];
  short8 o;
  o[0] = (short)f2b(a.x); o[1] = (short)f2b(a.y);
  o[2] = (short)f2b(a.z); o[3] = (short)f2b(a.w);
  o[4] = (short)f2b(b.x); o[5] = (short)f2b(b.y);
  o[6] = (short)f2b(b.z); o[7] = (short)f2b(b.w);
  *(short8*)(dst + (size_t)j * 8) = o;
}

// ---- all-4 weight transpose + convert in one launch: z selects the weight ----
__global__ __launch_bounds__(256) void transpose4_k(
    const float* __restrict__ Wq, const float* __restrict__ Wk,
    const float* __restrict__ Wv, const float* __restrict__ Wo,
    u16* __restrict__ dst4) {
  const float* src = (blockIdx.z == 0) ? Wq
                   : (blockIdx.z == 1) ? Wk
                   : (blockIdx.z == 2) ? Wv : Wo;
  u16* dst = dst4 + (size_t)blockIdx.z * HDIM * HDIM;
  __shared__ float tile[32][33];
  int tx = threadIdx.x, ty = threadIdx.y;  // 32 x 8
  int x = blockIdx.x * 32 + tx;
  int y0 = blockIdx.y * 32;
#pragma unroll
  for (int j = 0; j < 32; j += 8)
    tile[ty + j][tx] = src[(size_t)(y0 + ty + j) * HDIM + x];
  __syncthreads();
  int x2 = y0 + tx;
  int y2 = blockIdx.x * 32;
#pragma unroll
  for (int j = 0; j < 32; j += 8)
    dst[(size_t)(y2 + ty + j) * HDIM + x2] = f2b(tile[tx][ty + j]);
}

// ------------- m97-structure tiled GEMM (128x128, BK=32) -------------
// Used for the merged K+V projection (M=2048, N=4096 -> 512 blocks = 2/CU).
// cmode: 0 = bf16 C row-major; 2 = f32 C row-major;
// cmode 3 = merged KV: nn<2048 -> K row-major (ldc), nn>=2048 -> Vt scatter at
// Cv+4194304 (Kb and Vt are adjacent in the workspace); bias2 covers nn>=2048.
__global__ __launch_bounds__(256) void gemm_bt(
    const u16* __restrict__ A, int lda,
    const u16* __restrict__ Bt, int ldb,
    void* __restrict__ Cv, int ldc,
    const float* __restrict__ bias, const float* __restrict__ bias2,
    float alpha, int M, int N, int K, int cmode) {
  __shared__ u16 As[128 * 32];  // [row][k], rows of 64B
  __shared__ u16 Bs[128 * 32];

  int lane = threadIdx.x & 63;
  int wave = threadIdx.x >> 6;
  // T1: XCD-aware bijective tile swizzle (grid count % 8 == 0)
  int gdx = gridDim.x;
  int id = blockIdx.y * gdx + blockIdx.x;
  int cpx = (gdx * gridDim.y) >> 3;
  int sid = (id & 7) * cpx + (id >> 3);
  int m0 = (sid / gdx) * 128;
  int n0 = (sid % gdx) * 128;
  int wm = (wave & 1) * 64;
  int wn = (wave >> 1) * 64;
  int row16 = lane & 15;
  int quad = lane >> 4;

  int sr = (lane >> 2);
  int sc = (lane & 3) * 8;

  f32x4 acc[4][4];
#pragma unroll
  for (int i = 0; i < 4; i++)
#pragma unroll
    for (int j = 0; j < 4; j++) acc[i][j] = (f32x4){0.f, 0.f, 0.f, 0.f};

  for (int k0 = 0; k0 < K; k0 += 32) {
#pragma unroll
    for (int t = 0; t < 2; t++) {
      int chunk = wave * 2 + t;
      int r = chunk * 16 + sr;
      const u16* ga = A + (size_t)(m0 + r) * lda + k0 + sc;
      const u16* gb = Bt + (size_t)(n0 + r) * ldb + k0 + sc;
      __builtin_amdgcn_global_load_lds((gas_u32*)ga, (las_u32*)(As + chunk * 512), 16, 0, 0);
      __builtin_amdgcn_global_load_lds((gas_u32*)gb, (las_u32*)(Bs + chunk * 512), 16, 0, 0);
    }
    __syncthreads();

    short8 af[4], bf[4];
#pragma unroll
    for (int mt = 0; mt < 4; mt++)
      af[mt] = *(const short8*)(As + (wm + mt * 16 + row16) * 32 + quad * 8);
#pragma unroll
    for (int nt = 0; nt < 4; nt++)
      bf[nt] = *(const short8*)(Bs + (wn + nt * 16 + row16) * 32 + quad * 8);
#pragma unroll
    for (int mt = 0; mt < 4; mt++)
#pragma unroll
      for (int nt = 0; nt < 4; nt++)
        acc[mt][nt] = __builtin_amdgcn_mfma_f32_16x16x32_bf16(
            __builtin_bit_cast(bf16x8, af[mt]), __builtin_bit_cast(bf16x8, bf[nt]),
            acc[mt][nt], 0, 0, 0);
    __syncthreads();
  }

#pragma unroll
  for (int nt = 0; nt < 4; nt++) {
    int nn = n0 + wn + nt * 16 + row16;
    float bv;
    if (cmode == 3) bv = (nn < 2048) ? bias[nn] : bias2[nn - 2048];
    else            bv = bias ? bias[nn] : 0.f;
#pragma unroll
    for (int mt = 0; mt < 4; mt++) {
#pragma unroll
      for (int r = 0; r < 4; r++) {
        int mm = m0 + wm + mt * 16 + quad * 4 + r;
        float val = (acc[mt][nt][r] + bv) * alpha;
        if (cmode == 2) {
          ((float*)Cv)[(size_t)mm * ldc + nn] = val;
        } else if (cmode == 3) {
          if (nn < 2048) {
            ((u16*)Cv)[(size_t)mm * ldc + nn] = f2b(val);
          } else {
            int nn2 = nn - 2048;
            int bb = mm >> 9, aa = mm & 511;
            int hh = nn2 >> 7, dd = nn2 & 127;
            ((u16*)Cv + 4194304)[((size_t)((bb * 16 + hh) * 128 + dd)) * 512 + aa] =
                f2b(val);
          }
        } else {
          ((u16*)Cv)[(size_t)mm * ldc + nn] = f2b(val);
        }
      }
    }
  }
}

// ---- big-GEMM: 256x128 tile, BK=32, 3-slot ring, 2 blocks/CU (round-8) ----
// Round-7 BUG (caused NaN): sp "(kt+2)%3" was computed with a branchy expression
// valid only for kt+2<=8; at kt=7 it produced slot index 3 -> OOB LDS write +
// never-staged slots -> garbage bf16 -> exp -> inf -> NaN. Fixed: incremental
// slot tracking, sp = (slot+2)%3 branch-safe for all kt.
// Ledger (lead 2): iter kt stages slot (kt+2)%3 (3 gload_lds); vmcnt(3) once per
// K-tile => slot kt+1 fully landed before iter kt+1 reads it. Clobber safety:
// slot (kt+2)%3 == (kt-1)%3; iter-(kt-1) ds_reads drained before its lgkmcnt(0)
// -> before its end barrier -> before iter-kt stage issues.
// 72 KiB LDS -> 2 blocks/CU, 4 waves/SIMD; 8 waves = 4M x 2N, per-wave 64x64.
__global__ __launch_bounds__(512, 4) void gemm_ring8(
    const u16* __restrict__ A, int lda,
    const u16* __restrict__ Bt, int ldb,
    void* __restrict__ Cv, int ldc,
    const float* __restrict__ bias, float alpha, int K, int cmode) {
  __shared__ u16 As[3][256 * 32];  // 48 KiB
  __shared__ u16 Bs[3][128 * 32];  // 24 KiB  (72 KiB total -> 2 blocks/CU)

  int tid = threadIdx.x;
  int lane = tid & 63, wave = tid >> 6;  // 8 waves: 4M x 2N
  int wr = wave >> 1, wc = wave & 1;
  int row16 = lane & 15, quad = lane >> 4;
  int cofs = (quad * 8) ^ (((row16 >> 1) & 3) << 3);  // read-side swizzle

  // T1: XCD-aware bijective tile swizzle (grid count % 8 == 0)
  int gdx = gridDim.x;  // N tiles (128 wide)
  int id = blockIdx.y * gdx + blockIdx.x;
  int cpx = (gdx * gridDim.y) >> 3;
  int sid = (id & 7) * cpx + (id >> 3);
  int n0 = (sid % gdx) * 128;
  int m0 = (sid / gdx) * 256;

  int r0 = tid >> 2;                          // 0..127
  int c0 = ((tid & 3) ^ ((r0 >> 1) & 3)) * 8; // pre-swizzled global col chunk

  f32x4 acc[4][4];
#pragma unroll
  for (int i = 0; i < 4; i++)
#pragma unroll
    for (int j = 0; j < 4; j++) acc[i][j] = (f32x4){0.f, 0.f, 0.f, 0.f};

  auto stage = [&](int slot, int k0) {
#pragma unroll
    for (int l = 0; l < 2; l++) {  // A: 256 rows x 32 cols
      int row = l * 128 + r0;
      __builtin_amdgcn_global_load_lds(
          (gas_u32*)(A + (size_t)(m0 + row) * lda + k0 + c0),
          (las_u32*)(&As[slot][(l * 512 + tid) * 8]), 16, 0, 0);
    }
    // B: 128 rows x 32 cols (exactly one 16B chunk per thread)
    __builtin_amdgcn_global_load_lds(
        (gas_u32*)(Bt + (size_t)(n0 + r0) * ldb + k0 + c0),
        (las_u32*)(&Bs[slot][(size_t)tid * 8]), 16, 0, 0);
  };

  int NT = K >> 5;  // K-tiles of 32 (NT >= 2)
  stage(0, 0);
  stage(1, 32);
  asm volatile("s_waitcnt vmcnt(3)" ::: "memory");  // slot 0 landed
  __builtin_amdgcn_s_barrier();

  int slot = 0;  // kt % 3, tracked incrementally (round-8 fix)
  for (int kt = 0; kt < NT; ++kt) {
    int sp = (slot >= 1) ? slot - 1 : 2;  // (slot+2) % 3, branch-safe
    bool pf = (kt + 2) < NT;
    const u16* as = &As[slot][0];
    const u16* bs = &Bs[slot][0];

    short8 af[4], bfr[4];
#pragma unroll
    for (int mi = 0; mi < 4; mi++)
      af[mi] = *(const short8*)(as + (wr * 64 + mi * 16 + row16) * 32 + cofs);
#pragma unroll
    for (int ni = 0; ni < 4; ni++)
      bfr[ni] = *(const short8*)(bs + (wc * 64 + ni * 16 + row16) * 32 + cofs);
    if (pf) stage(sp, (kt + 2) << 5);
    if (pf) { asm volatile("s_waitcnt vmcnt(3)" ::: "memory"); }
    else    { asm volatile("s_waitcnt vmcnt(0)" ::: "memory"); }
    __builtin_amdgcn_s_barrier();
    asm volatile("s_waitcnt lgkmcnt(0)" ::: "memory");
    __builtin_amdgcn_s_setprio(1);
#pragma unroll
    for (int mi = 0; mi < 4; mi++)
#pragma unroll
      for (int ni = 0; ni < 4; ni++)
        acc[mi][ni] = __builtin_amdgcn_mfma_f32_16x16x32_bf16(
            __builtin_bit_cast(bf16x8, af[mi]), __builtin_bit_cast(bf16x8, bfr[ni]),
            acc[mi][ni], 0, 0, 0);
    __builtin_amdgcn_s_setprio(0);
    __builtin_amdgcn_s_barrier();
    slot = (slot >= 2) ? 0 : slot + 1;
  }

#pragma unroll
  for (int ni = 0; ni < 4; ni++) {
    int nn = n0 + wc * 64 + ni * 16 + row16;
    float bv = bias ? bias[nn] : 0.f;
#pragma unroll
    for (int mi = 0; mi < 4; mi++) {
#pragma unroll
      for (int r = 0; r < 4; r++) {
        int mm = m0 + wr * 64 + mi * 16 + quad * 4 + r;
        float val = (acc[mi][ni][r] + bv) * alpha;
        if (cmode == 2) ((float*)Cv)[(size_t)mm * ldc + nn] = val;
        else            ((u16*)Cv)[(size_t)mm * ldc + nn] = f2b(val);
      }
    }
  }
}

// ---------------- fused flash attention (round-6, verified 565.9us total) ----------------
// 256 thr = 4 waves, each owns 32 q-rows. Per-tile global_load_lds staging.
// LDS XOR-swizzle col^((row&7)<<3) on KP/Vs. No setprio (m190).
// P-write -> PV barrier removed (wave-private P rows).
// XCD-chunked block swizzle: XCD k serves bh in [k*8, k*8+8).
__global__ __launch_bounds__(256) void flash_k(
    const u16* __restrict__ Q, const u16* __restrict__ K,
    const u16* __restrict__ Vt, const float* __restrict__ mask,
    u16* __restrict__ Ctx) {
  __shared__ u16 KP[128 * 128];  // K-tile [key][dh], then P-tile [q][key]
  __shared__ u16 Vs[128 * 128];  // V-tile [dh][key]

  int id = blockIdx.y * gridDim.x + blockIdx.x;
  int sid = (id & 7) * 128 + (id >> 3);
  int qt = sid & 15, bh = sid >> 4;
  int b = bh >> 4, h = bh & 15;
  int q0 = qt * 128;

  int lane = threadIdx.x & 63, wave = threadIdx.x >> 6;
  int row16 = lane & 15, quad = lane >> 4;
  int wq = wave * 32;  // wave's 32 q-rows
  int swr = (row16 & 7) << 3;  // read-side swizzle

  const u16* qbase = Q + ((size_t)(b * SEQ + q0)) * HDIM + h * DHEAD;
  const u16* kbase = K + ((size_t)b * AUD) * HDIM + h * DHEAD;
  const u16* vbase = Vt + ((size_t)(b * NHEAD + h)) * DHEAD * AUD;
  const float* mp = mask + b * AUD;

  short8 qf[2][4];
#pragma unroll
  for (int mt = 0; mt < 2; mt++)
#pragma unroll
    for (int ks = 0; ks < 4; ks++)
      qf[mt][ks] = *(const short8*)(qbase + (size_t)(wq + mt * 16 + row16) * HDIM +
                                    ks * 32 + quad * 8);

  f32x4 oacc[2][8];
  float lacc[2][4];
#pragma unroll
  for (int mt = 0; mt < 2; mt++) {
#pragma unroll
    for (int nt = 0; nt < 8; nt++) oacc[mt][nt] = (f32x4){0.f, 0.f, 0.f, 0.f};
#pragma unroll
    for (int r = 0; r < 4; r++) lacc[mt][r] = 0.f;
  }

  int sl = (lane >> 4);
  int scol = (lane & 15) * 8;

  for (int kt = 0; kt < 4; kt++) {
#pragma unroll
    for (int t = 0; t < 8; t++) {
      int c = wave * 8 + t;
      int r = c * 4 + sl;
      int csw = scol ^ ((r & 7) << 3);
      __builtin_amdgcn_global_load_lds(
          (gas_u32*)(kbase + (size_t)(kt * 128 + r) * HDIM + csw),
          (las_u32*)(KP + c * 512), 16, 0, 0);
      __builtin_amdgcn_global_load_lds(
          (gas_u32*)(vbase + (size_t)r * AUD + kt * 128 + csw),
          (las_u32*)(Vs + c * 512), 16, 0, 0);
    }
    __syncthreads();

    f32x4 sacc[2][8];
#pragma unroll
    for (int mt = 0; mt < 2; mt++)
#pragma unroll
      for (int nt = 0; nt < 8; nt++) sacc[mt][nt] = (f32x4){0.f, 0.f, 0.f, 0.f};
#pragma unroll
    for (int ks = 0; ks < 4; ks++) {
      short8 bf[8];
      int cofs = (ks * 32 + quad * 8) ^ swr;
#pragma unroll
      for (int nt = 0; nt < 8; nt++)
        bf[nt] = *(const short8*)(KP + (nt * 16 + row16) * 128 + cofs);
#pragma unroll
      for (int mt = 0; mt < 2; mt++)
#pragma unroll
        for (int nt = 0; nt < 8; nt++)
          sacc[mt][nt] = __builtin_amdgcn_mfma_f32_16x16x32_bf16(
              __builtin_bit_cast(bf16x8, qf[mt][ks]), __builtin_bit_cast(bf16x8, bf[nt]),
              sacc[mt][nt], 0, 0, 0);
    }

#pragma unroll
    for (int nt = 0; nt < 8; nt++) {
      float mval = mp[kt * 128 + nt * 16 + row16] * (-10000.0f);
#pragma unroll
      for (int mt = 0; mt < 2; mt++)
#pragma unroll
        for (int r = 0; r < 4; r++) {
          float e = __expf(sacc[mt][nt][r] + mval);
          sacc[mt][nt][r] = e;
          lacc[mt][r] += e;
        }
    }
    __syncthreads();  // all waves done reading KP-as-K

    // write P (bf16) into KP as [q][key], swizzled by q-row
#pragma unroll
    for (int mt = 0; mt < 2; mt++)
#pragma unroll
      for (int nt = 0; nt < 8; nt++)
#pragma unroll
        for (int r = 0; r < 4; r++) {
          int prow = wq + mt * 16 + quad * 4 + r;
          KP[prow * 128 + ((nt * 16 + row16) ^ ((prow & 7) << 3))] =
              f2b(sacc[mt][nt][r]);
        }
    // (no barrier: each wave reads back only its own 32 P-rows)

    // O += P @ V
#pragma unroll
    for (int ks = 0; ks < 4; ks++) {
      short8 af[2], bf[8];
      int cofs = (ks * 32 + quad * 8) ^ swr;
#pragma unroll
      for (int mt = 0; mt < 2; mt++)
        af[mt] = *(const short8*)(KP + (wq + mt * 16 + row16) * 128 + cofs);
#pragma unroll
      for (int nt = 0; nt < 8; nt++)
        bf[nt] = *(const short8*)(Vs + (nt * 16 + row16) * 128 + cofs);
#pragma unroll
      for (int mt = 0; mt < 2; mt++)
#pragma unroll
        for (int nt = 0; nt < 8; nt++)
          oacc[mt][nt] = __builtin_amdgcn_mfma_f32_16x16x32_bf16(
              __builtin_bit_cast(bf16x8, af[mt]), __builtin_bit_cast(bf16x8, bf[nt]),
              oacc[mt][nt], 0, 0, 0);
    }
    __syncthreads();  // done reading KP(P)/Vs before next stage
  }

  // reduce l over the 16 lanes of each quad (keys dimension)
#pragma unroll
  for (int mt = 0; mt < 2; mt++)
#pragma unroll
    for (int r = 0; r < 4; r++) {
      float s = lacc[mt][r];
      for (int off = 1; off < 16; off <<= 1) s += __shfl_xor(s, off, 64);
      lacc[mt][r] = 1.0f / s;
    }

  // write ctx: C/D layout col=dh (lane&15), row=q (quad*4+r)
  u16* cb = Ctx + ((size_t)(b * SEQ + q0 + wq)) * HDIM + h * DHEAD;
#pragma unroll
  for (int mt = 0; mt < 2; mt++)
#pragma unroll
    for (int nt = 0; nt < 8; nt++)
#pragma unroll
      for (int r = 0; r < 4; r++)
        cb[(size_t)(mt * 16 + quad * 4 + r) * HDIM + nt * 16 + row16] =
            f2b(oacc[mt][nt][r] * lacc[mt][r]);
}

// ---- residual + LayerNorm (f32 in/out): out = LN(O + hs)*gamma + beta, in place ----
__global__ __launch_bounds__(256) void ln_k(const float* O,
                                            const float* __restrict__ hs,
                                            const float* __restrict__ gamma,
                                            const float* __restrict__ beta,
                                            float* out) {
  size_t rowoff = (size_t)blockIdx.x * HDIM;
  float x[8], sum = 0.f, sq = 0.f;
#pragma unroll
  for (int i = 0; i < 8; i++) {
    int idx = threadIdx.x + 256 * i;
    float v = O[rowoff + idx] + hs[rowoff + idx];
    x[i] = v;
    sum += v;
    sq += v * v;
  }
  for (int off = 32; off; off >>= 1) {
    sum += __shfl_xor(sum, off, 64);
    sq += __shfl_xor(sq, off, 64);
  }
  __shared__ float red[8];
  int wave = threadIdx.x >> 6, lane = threadIdx.x & 63;
  if (lane == 0) { red[wave] = sum; red[4 + wave] = sq; }
  __syncthreads();
  sum = red[0] + red[1] + red[2] + red[3];
  sq = red[4] + red[5] + red[6] + red[7];
  float mu = sum * (1.0f / HDIM);
  float var = sq * (1.0f / HDIM) - mu * mu;
  float inv = rsqrtf(var + 1e-5f);
#pragma unroll
  for (int i = 0; i < 8; i++) {
    int idx = threadIdx.x + 256 * i;
    out[rowoff + idx] = (x[i] - mu) * inv * gamma[idx] + beta[idx];
  }
}

extern "C" void kernel_launch(void* const* d_in, const int* in_sizes, int n_in,
                              void* d_out, int out_size, void* d_ws, size_t ws_size,
                              hipStream_t stream) {
  (void)in_sizes; (void)n_in; (void)out_size; (void)ws_size;
  const float* hs   = (const float*)d_in[0];
  const float* at   = (const float*)d_in[1];
  const float* mask = (const float*)d_in[2];
  const float* Wq = (const float*)d_in[3];  const float* bq = (const float*)d_in[4];
  const float* Wk = (const float*)d_in[5];  const float* bk = (const float*)d_in[6];
  const float* Wv = (const float*)d_in[7];  const float* bv = (const float*)d_in[8];
  const float* Wo = (const float*)d_in[9];  const float* bo = (const float*)d_in[10];
  const float* gamma = (const float*)d_in[11];
  const float* beta  = (const float*)d_in[12];
  float* out = (float*)d_out;
  u16* ws = (u16*)d_ws;

  // workspace (bf16 elements). Total 79,691,776 els = 159.4 MB (ws has 256 MB).
  u16* hsb = ws;               // 16,777,216  bf16(hidden_states)
  u16* atb = ws + 16777216;    //  4,194,304  bf16(audio_tokens)
  u16* wT4 = ws + 20971520;    // 16,777,216  4x transposed bf16 weights
  u16* Q   = ws + 37748736;    // 16,777,216  (8192 x 2048, pre-scaled)
  u16* Kb  = ws + 54525952;    //  4,194,304  (2048 x 2048)
  u16* Vt  = ws + 58720256;    //  4,194,304  [b,h,d,a]  (== Kb + 4194304)
  u16* Ctx = ws + 62914560;    // 16,777,216  (8192 x 2048)
  u16* wTq = wT4;
  u16* wTk = wT4 + 4194304;
  // wTv = wT4 + 8388608 (contiguous after wTk -> merged KV GEMM reads rows 0..4095)
  u16* wTo = wT4 + 12582912;
  // O (pre-LN, f32) lives in d_out; ln_k is same-thread in-place: safe.

  // both input converts in one launch
  cvt2_k<<<10240, 256, 0, stream>>>(hs, hsb, 2097152, at, atb, 524288);
  // all 4 weight transposes in one launch
  transpose4_k<<<dim3(64, 64, 4), dim3(32, 8), 0, stream>>>(Wq, Wk, Wv, Wo, wT4);

  const float qscale = 0.08838834764831845f;  // 1/sqrt(128)

  // Q = (hs @ Wq + bq) * qscale : M=8192 N=2048 K=2048 (256x128 tiles -> 16x32)
  gemm_ring8<<<dim3(16, 32), 512, 0, stream>>>(hsb, HDIM, wTq, HDIM, Q, HDIM,
                                               bq, qscale, 2048, 0);
  // merged K|V = at @ [Wk|Wv] : M=2048 N=4096 (128x128 tiles -> 32x16 = 512 blocks)
  // nn<2048 -> Kb row-major; nn>=2048 -> Vt scatter (Vt = Kb + 4194304)
  gemm_bt<<<dim3(32, 16), 256, 0, stream>>>(atb, HDIM, wTk, HDIM, Kb, 2048,
                                            bk, bv, 1.0f, 2048, 4096, 2048, 3);

  // fused attention: Ctx = softmax(Q K^T + mask) V
  flash_k<<<dim3(SEQ / 128, BATCH * NHEAD), 256, 0, stream>>>(Q, Kb, Vt, mask, Ctx);

  // O = Ctx @ Wo + bo : M=8192, f32 into d_out (cmode=2)
  gemm_ring8<<<dim3(16, 32), 512, 0, stream>>>(Ctx, HDIM, wTo, HDIM, out, HDIM,
                                               bo, 1.0f, 2048, 2);
  // out = LayerNorm(O + hs) * gamma + beta  (f32, in place over d_out)
  ln_k<<<8192, 256, 0, stream>>>(out, hs, gamma, beta, out);
}